// Round 20
// baseline (427.355 us; speedup 1.0000x reference)
//
#include <hip/hip_runtime.h>
#include <hip/hip_bf16.h>

#define DD 128      // feature dim
#define PAD_I 64    // max item in-degree (Poisson(16); P(overflow) ~ 1e-6, guarded)
#define PAD_U 48    // max user in-degree (Poisson(8);  P(overflow) ~ 1e-9, guarded)

typedef __attribute__((ext_vector_type(8))) short bf16x8;
typedef __attribute__((ext_vector_type(4))) float f32x4;

// manual RNE fp32 -> bf16 (one-time weight prep only)
__device__ __forceinline__ unsigned short rne_bf16(float x) {
    unsigned int u = __float_as_uint(x);
    return (unsigned short)((u + 0x7FFFu + ((u >> 16) & 1u)) >> 16);
}

// load 8 contiguous fp32 (optionally relu) -> hi+lo bf16 frags (v_cvt_pk_bf16_f32 path)
template <bool R>
__device__ __forceinline__ void load_split8(const float* __restrict__ p,
                                            bf16x8& hf, bf16x8& lf) {
    float4 v0 = *reinterpret_cast<const float4*>(p);
    float4 v1 = *reinterpret_cast<const float4*>(p + 4);
    float x[8] = {v0.x, v0.y, v0.z, v0.w, v1.x, v1.y, v1.z, v1.w};
#pragma unroll
    for (int j = 0; j < 8; j += 2) {
        float a = R ? fmaxf(x[j], 0.f) : x[j];
        float b = R ? fmaxf(x[j + 1], 0.f) : x[j + 1];
        __hip_bfloat162 h2 = __float22bfloat162_rn(make_float2(a, b));
        float2 hr = __bfloat1622float2(h2);
        __hip_bfloat162 l2 = __float22bfloat162_rn(make_float2(a - hr.x, b - hr.y));
        hf[j]     = (short)__bfloat16_as_ushort(h2.x);
        hf[j + 1] = (short)__bfloat16_as_ushort(h2.y);
        lf[j]     = (short)__bfloat16_as_ushort(l2.x);
        lf[j + 1] = (short)__bfloat16_as_ushort(l2.y);
    }
}

// one 128-col GEMM stage vs packed planes, accumulating 3 split products
#define STAGE_MFMA(AH, AL, WH_, WL_, ACC)                                               \
    _Pragma("unroll")                                                                   \
    for (int kc = 0; kc < 4; ++kc) {                                                    \
        const size_t fb = ((size_t)(kc * 8) * 64 + l) * 8;                              \
        bf16x8 bh[8], bl[8];                                                            \
        _Pragma("unroll") for (int t = 0; t < 8; ++t)                                   \
            bh[t] = *reinterpret_cast<const bf16x8*>((WH_) + fb + t * 512);             \
        _Pragma("unroll") for (int t = 0; t < 8; ++t)                                   \
            bl[t] = *reinterpret_cast<const bf16x8*>((WL_) + fb + t * 512);             \
        _Pragma("unroll") for (int t = 0; t < 8; ++t)                                   \
            ACC[t] = __builtin_amdgcn_mfma_f32_16x16x32_bf16(AH[kc], bh[t], ACC[t], 0, 0, 0); \
        _Pragma("unroll") for (int t = 0; t < 8; ++t)                                   \
            ACC[t] = __builtin_amdgcn_mfma_f32_16x16x32_bf16(AL[kc], bh[t], ACC[t], 0, 0, 0); \
        _Pragma("unroll") for (int t = 0; t < 8; ++t)                                   \
            ACC[t] = __builtin_amdgcn_mfma_f32_16x16x32_bf16(AH[kc], bl[t], ACC[t], 0, 0, 0); \
    }

// ---------------- setup kernels (merged) ----------------

struct W12 { const float* p[12]; };

// wsplit (packed fragment-order hi/lo planes) + zero both degree arrays.
// Packed p = ((kc*8 + t)*64 + lane)*8 + j  <->  W[t*16 + (lane&15)][kc*32 + (lane>>4)*8 + j]
__global__ __launch_bounds__(256) void setup_k(W12 ws, unsigned short* __restrict__ hi,
                                               unsigned short* __restrict__ lo,
                                               int* __restrict__ deg_i, int ni,
                                               int* __restrict__ deg_u, int nu) {
    int idx = blockIdx.x * 256 + threadIdx.x;
    if (idx < 12 * DD * DD) {
        int m = idx >> 14, pk = idx & 16383;
        int j = pk & 7, lane = (pk >> 3) & 63, t = (pk >> 9) & 7, kc = (pk >> 12) & 3;
        int src = (t * 16 + (lane & 15)) * DD + kc * 32 + (lane >> 4) * 8 + j;
        float x = ws.p[m][src];
        unsigned short h = rne_bf16(x);
        float r = x - __uint_as_float((unsigned int)h << 16);
        hi[idx] = h;
        lo[idx] = rne_bf16(r);
    }
    if (idx < ni) deg_i[idx] = 0;
    if (idx < nu) deg_u[idx] = 0;
}

// both adjacency fills in one dispatch: e < E -> ue edge, else iu edge
__global__ __launch_bounds__(256) void fill2_k(const int* __restrict__ ue_src,
                                               const int* __restrict__ ue_dst,
                                               int* __restrict__ deg_i, int* __restrict__ adj_i,
                                               const int* __restrict__ iu_src,
                                               const int* __restrict__ iu_dst,
                                               int* __restrict__ deg_u, int* __restrict__ adj_u,
                                               int E) {
    int e = blockIdx.x * 256 + threadIdx.x;
    if (e < E) {
        int d = ue_dst[e];
        int slot = atomicAdd(&deg_i[d], 1);
        if (slot < PAD_I) adj_i[(size_t)d * PAD_I + slot] = ue_src[e];
    } else if (e < 2 * E) {
        int e2 = e - E;
        int d = iu_dst[e2];
        int slot = atomicAdd(&deg_u[d], 1);
        if (slot < PAD_U) adj_u[(size_t)d * PAD_U + slot] = iu_src[e2];
    }
}

// gather body (r15-verified): 4 rows/block, 1 wave/row. 4 x 16-lane groups:
// group p = lane>>4 owns edges e == p (mod 4); lane covers cols c*8..c*8+7.
// DIRECT pl[j] index loads (NO shfl — divergent-exec shfl is undefined, r9 lesson).
template <bool RELU>
__device__ __forceinline__ void gather_body(const float* __restrict__ feat,
                                            const int* __restrict__ cur,
                                            const int* __restrict__ pad, int PAD,
                                            float* __restrict__ out, int N, int blk) {
    int row = blk * 4 + (threadIdx.x >> 6);
    if (row >= N) return;
    int lane = threadIdx.x & 63;
    int p = lane >> 4, c = lane & 15;
    int deg = cur[row]; if (deg > PAD) deg = PAD;
    const int* pl = pad + (size_t)row * PAD;

    float4 a0 = make_float4(0.f, 0.f, 0.f, 0.f);
    float4 a1 = make_float4(0.f, 0.f, 0.f, 0.f);
    float4 b0 = make_float4(0.f, 0.f, 0.f, 0.f);
    float4 b1 = make_float4(0.f, 0.f, 0.f, 0.f);
    int j = p;
    for (; j + 4 < deg; j += 8) {
        int s0 = pl[j];
        int s1 = pl[j + 4];
        const float* q0 = feat + (size_t)s0 * DD + c * 8;
        const float* q1 = feat + (size_t)s1 * DD + c * 8;
        float4 u0 = *reinterpret_cast<const float4*>(q0);
        float4 u1 = *reinterpret_cast<const float4*>(q0 + 4);
        float4 u2 = *reinterpret_cast<const float4*>(q1);
        float4 u3 = *reinterpret_cast<const float4*>(q1 + 4);
        if (RELU) {
            u0.x = fmaxf(u0.x, 0.f); u0.y = fmaxf(u0.y, 0.f); u0.z = fmaxf(u0.z, 0.f); u0.w = fmaxf(u0.w, 0.f);
            u1.x = fmaxf(u1.x, 0.f); u1.y = fmaxf(u1.y, 0.f); u1.z = fmaxf(u1.z, 0.f); u1.w = fmaxf(u1.w, 0.f);
            u2.x = fmaxf(u2.x, 0.f); u2.y = fmaxf(u2.y, 0.f); u2.z = fmaxf(u2.z, 0.f); u2.w = fmaxf(u2.w, 0.f);
            u3.x = fmaxf(u3.x, 0.f); u3.y = fmaxf(u3.y, 0.f); u3.z = fmaxf(u3.z, 0.f); u3.w = fmaxf(u3.w, 0.f);
        }
        a0.x += u0.x; a0.y += u0.y; a0.z += u0.z; a0.w += u0.w;
        a1.x += u1.x; a1.y += u1.y; a1.z += u1.z; a1.w += u1.w;
        b0.x += u2.x; b0.y += u2.y; b0.z += u2.z; b0.w += u2.w;
        b1.x += u3.x; b1.y += u3.y; b1.z += u3.z; b1.w += u3.w;
    }
    if (j < deg) {
        int s = pl[j];
        const float* q = feat + (size_t)s * DD + c * 8;
        float4 u0 = *reinterpret_cast<const float4*>(q);
        float4 u1 = *reinterpret_cast<const float4*>(q + 4);
        if (RELU) {
            u0.x = fmaxf(u0.x, 0.f); u0.y = fmaxf(u0.y, 0.f); u0.z = fmaxf(u0.z, 0.f); u0.w = fmaxf(u0.w, 0.f);
            u1.x = fmaxf(u1.x, 0.f); u1.y = fmaxf(u1.y, 0.f); u1.z = fmaxf(u1.z, 0.f); u1.w = fmaxf(u1.w, 0.f);
        }
        a0.x += u0.x; a0.y += u0.y; a0.z += u0.z; a0.w += u0.w;
        a1.x += u1.x; a1.y += u1.y; a1.z += u1.z; a1.w += u1.w;
    }
    a0.x += b0.x; a0.y += b0.y; a0.z += b0.z; a0.w += b0.w;
    a1.x += b1.x; a1.y += b1.y; a1.z += b1.z; a1.w += b1.w;

#pragma unroll
    for (int off = 16; off <= 32; off <<= 1) {
        a0.x += __shfl_xor(a0.x, off); a0.y += __shfl_xor(a0.y, off);
        a0.z += __shfl_xor(a0.z, off); a0.w += __shfl_xor(a0.w, off);
        a1.x += __shfl_xor(a1.x, off); a1.y += __shfl_xor(a1.y, off);
        a1.z += __shfl_xor(a1.z, off); a1.w += __shfl_xor(a1.w, off);
    }
    if (p == 0) {
        float iv = 1.0f / (float)(deg > 1 ? deg : 1);
        a0.x *= iv; a0.y *= iv; a0.z *= iv; a0.w *= iv;
        a1.x *= iv; a1.y *= iv; a1.z *= iv; a1.w *= iv;
        float* o = out + (size_t)row * DD + c * 8;
        *reinterpret_cast<float4*>(o) = a0;
        *reinterpret_cast<float4*>(o + 4) = a1;
    }
}

// standalone gather (L2 user gather)
template <bool RELU>
__global__ __launch_bounds__(256) void gather_mean_k(const float* __restrict__ feat,
                                                     const int* __restrict__ cur,
                                                     const int* __restrict__ pad, int PAD,
                                                     float* __restrict__ out, int N) {
    gather_body<RELU>(feat, cur, pad, PAD, out, N, blockIdx.x);
}

// merged dual gather (L1): task1 (nb1 blocks) + task2 (nb2 blocks), 1:2 block stripe
template <bool RELU1, bool RELU2>
__global__ __launch_bounds__(256) void gather2_k(
        const float* __restrict__ feat1, const int* __restrict__ cur1,
        const int* __restrict__ pad1, int PAD1, float* __restrict__ out1, int N1, int nb1,
        const float* __restrict__ feat2, const int* __restrict__ cur2,
        const int* __restrict__ pad2, int PAD2, float* __restrict__ out2, int N2, int nb2) {
    int b = blockIdx.x;
    int which, idx;
    if (nb2 == 2 * nb1) {
        int tri = b / 3, rem = b - tri * 3;
        if (rem == 0) { which = 0; idx = tri; }
        else          { which = 1; idx = 2 * tri + rem - 1; }
    } else {
        which = (b < nb1) ? 0 : 1;
        idx = which ? (b - nb1) : b;
    }
    if (which == 0) gather_body<RELU1>(feat1, cur1, pad1, PAD1, out1, N1, idx);
    else            gather_body<RELU2>(feat2, cur2, pad2, PAD2, out2, N2, idx);
}

// ---------------- split-bf16 MFMA GEMM kernels ----------------
// FULL 3-product split: ah*bh + al*bh + ah*bl (~2^-18 residual).
// mfma_f32_16x16x32_bf16: A/B row = lane&15, k = (lane>>4)*8 + j; C/D col = lane&15,
// row = (lane>>4)*4 + reg.

// MERGED item layer-1 (64-row blocks, 16 rows/wave):
//   xi frags loaded ONCE (kept for uiWs operand);
//   h = relu(xi@pW1+pb1) -> LDS -> frags;
//   v = agg - (h@pW2+pb2)*(deg>0)   [agg read from Ia, FINI in registers]
//   v -> LDS -> frags;  xi1 = relu(v@uiWn + uibn + xi@uiWs + uibs) -> Ia
template <bool RELX>
__global__ __launch_bounds__(256) void item1_k(
        const float* __restrict__ X,
        const unsigned short* __restrict__ P1h, const unsigned short* __restrict__ P1l,
        const float* __restrict__ pb1,
        const unsigned short* __restrict__ P2h, const unsigned short* __restrict__ P2l,
        const float* __restrict__ pb2,
        const unsigned short* __restrict__ Nh,  const unsigned short* __restrict__ Nl,
        const float* __restrict__ bn,
        const unsigned short* __restrict__ Sh,  const unsigned short* __restrict__ Sl,
        const float* __restrict__ bs,
        float* __restrict__ Ia, int N, const int* __restrict__ deg) {
    __shared__ __align__(16) float hl[64][DD + 4];   // h, then reused for v

    const int tid = threadIdx.x;
    const int w = tid >> 6, l = tid & 63;
    const int l15 = l & 15, lq = l >> 4;

    const int rowA = blockIdx.x * 64 + w * 16 + l15;
    const int rA = rowA < N ? rowA : N - 1;
    const float* xp = X + (size_t)rA * DD;

    bf16x8 axh[4], axl[4];
#pragma unroll
    for (int kc = 0; kc < 4; ++kc)
        load_split8<RELX>(xp + kc * 32 + lq * 8, axh[kc], axl[kc]);

    f32x4 acc[8];
#pragma unroll
    for (int t = 0; t < 8; ++t) acc[t] = (f32x4){0.f, 0.f, 0.f, 0.f};

    STAGE_MFMA(axh, axl, P1h, P1l, acc)

    const int lr0 = w * 16 + lq * 4;
#pragma unroll
    for (int t = 0; t < 8; ++t) {
        const int col = t * 16 + l15;
        const float b = pb1[col];
#pragma unroll
        for (int r = 0; r < 4; ++r)
            hl[lr0 + r][col] = fmaxf(acc[t][r] + b, 0.f);
    }
    __syncthreads();

    bf16x8 ahh[4], ahl[4];
#pragma unroll
    for (int kc = 0; kc < 4; ++kc)
        load_split8<false>(&hl[w * 16 + l15][kc * 32 + lq * 8], ahh[kc], ahl[kc]);
    __syncthreads();

#pragma unroll
    for (int t = 0; t < 8; ++t) acc[t] = (f32x4){0.f, 0.f, 0.f, 0.f};
    STAGE_MFMA(ahh, ahl, P2h, P2l, acc)

#pragma unroll
    for (int t = 0; t < 8; ++t) {
        const int col = t * 16 + l15;
        const float b2v = pb2[col];
#pragma unroll
        for (int r = 0; r < 4; ++r) {
            const int grow = blockIdx.x * 64 + lr0 + r;
            const int gr = grow < N ? grow : N - 1;
            float fl = deg[gr] > 0 ? 1.f : 0.f;
            float ag = Ia[(size_t)gr * DD + col];
            hl[lr0 + r][col] = ag - (acc[t][r] + b2v) * fl;
        }
    }
    __syncthreads();

    bf16x8 avh[4], avl[4];
#pragma unroll
    for (int kc = 0; kc < 4; ++kc)
        load_split8<false>(&hl[w * 16 + l15][kc * 32 + lq * 8], avh[kc], avl[kc]);

#pragma unroll
    for (int t = 0; t < 8; ++t) acc[t] = (f32x4){0.f, 0.f, 0.f, 0.f};
    STAGE_MFMA(avh, avl, Nh, Nl, acc)
    STAGE_MFMA(axh, axl, Sh, Sl, acc)

#pragma unroll
    for (int t = 0; t < 8; ++t) {
        const int col = t * 16 + l15;
        const float bias = bn[col] + bs[col];
#pragma unroll
        for (int r = 0; r < 4; ++r) {
            const int grow = blockIdx.x * 64 + lr0 + r;
            if (grow >= N) continue;
            Ia[(size_t)grow * DD + col] = fmaxf(acc[t][r] + bias, 0.f);
        }
    }
}

// shared dual-GEMM accumulator: 128-row blocks, 32 rows/wave via 2 rowgroups
template <bool RELX2>
__device__ __forceinline__ void dual_acc(
        const float* __restrict__ X1,
        const unsigned short* __restrict__ W1h, const unsigned short* __restrict__ W1l,
        const float* __restrict__ X2,
        const unsigned short* __restrict__ W2h, const unsigned short* __restrict__ W2l,
        int N, int base, int l, int lq, int l15, f32x4 (&acc)[2][8]) {
    int rA[2];
#pragma unroll
    for (int g = 0; g < 2; ++g) {
        int r = base + g * 16 + l15;
        rA[g] = r < N ? r : N - 1;
    }
    {   // ---- X1 @ W1 ----
        bf16x8 ah[2][4], al[2][4];
#pragma unroll
        for (int g = 0; g < 2; ++g)
#pragma unroll
            for (int kc = 0; kc < 4; ++kc)
                load_split8<false>(X1 + (size_t)rA[g] * DD + kc * 32 + lq * 8, ah[g][kc], al[g][kc]);
#pragma unroll
        for (int kc = 0; kc < 4; ++kc) {
            const size_t fb = ((size_t)(kc * 8) * 64 + l) * 8;
            bf16x8 bh[8], bl[8];
#pragma unroll
            for (int t = 0; t < 8; ++t) bh[t] = *reinterpret_cast<const bf16x8*>(W1h + fb + t * 512);
#pragma unroll
            for (int t = 0; t < 8; ++t) bl[t] = *reinterpret_cast<const bf16x8*>(W1l + fb + t * 512);
#pragma unroll
            for (int g = 0; g < 2; ++g) {
#pragma unroll
                for (int t = 0; t < 8; ++t)
                    acc[g][t] = __builtin_amdgcn_mfma_f32_16x16x32_bf16(ah[g][kc], bh[t], acc[g][t], 0, 0, 0);
#pragma unroll
                for (int t = 0; t < 8; ++t)
                    acc[g][t] = __builtin_amdgcn_mfma_f32_16x16x32_bf16(al[g][kc], bh[t], acc[g][t], 0, 0, 0);
#pragma unroll
                for (int t = 0; t < 8; ++t)
                    acc[g][t] = __builtin_amdgcn_mfma_f32_16x16x32_bf16(ah[g][kc], bl[t], acc[g][t], 0, 0, 0);
            }
        }
    }
    {   // ---- X2 @ W2 ----
        bf16x8 ah[2][4], al[2][4];
#pragma unroll
        for (int g = 0; g < 2; ++g)
#pragma unroll
            for (int kc = 0; kc < 4; ++kc)
                load_split8<RELX2>(X2 + (size_t)rA[g] * DD + kc * 32 + lq * 8, ah[g][kc], al[g][kc]);
#pragma unroll
        for (int kc = 0; kc < 4; ++kc) {
            const size_t fb = ((size_t)(kc * 8) * 64 + l) * 8;
            bf16x8 bh[8], bl[8];
#pragma unroll
            for (int t = 0; t < 8; ++t) bh[t] = *reinterpret_cast<const bf16x8*>(W2h + fb + t * 512);
#pragma unroll
            for (int t = 0; t < 8; ++t) bl[t] = *reinterpret_cast<const bf16x8*>(W2l + fb + t * 512);
#pragma unroll
            for (int g = 0; g < 2; ++g) {
#pragma unroll
                for (int t = 0; t < 8; ++t)
                    acc[g][t] = __builtin_amdgcn_mfma_f32_16x16x32_bf16(ah[g][kc], bh[t], acc[g][t], 0, 0, 0);
#pragma unroll
                for (int t = 0; t < 8; ++t)
                    acc[g][t] = __builtin_amdgcn_mfma_f32_16x16x32_bf16(al[g][kc], bh[t], acc[g][t], 0, 0, 0);
#pragma unroll
                for (int t = 0; t < 8; ++t)
                    acc[g][t] = __builtin_amdgcn_mfma_f32_16x16x32_bf16(ah[g][kc], bl[t], acc[g][t], 0, 0, 0);
            }
        }
    }
}

// dual GEMM: out = relu( X1@W1^T + b1 + X2@W2^T + b2 );  out may alias X1
template <bool RELX2>
__global__ __launch_bounds__(256) void gemm_dual_k(
        const float* __restrict__ X1,
        const unsigned short* __restrict__ W1h, const unsigned short* __restrict__ W1l,
        const float* __restrict__ B1,
        const float* __restrict__ X2,
        const unsigned short* __restrict__ W2h, const unsigned short* __restrict__ W2l,
        const float* __restrict__ B2,
        float* __restrict__ out, int N) {
    const int tid = threadIdx.x;
    const int w = tid >> 6, l = tid & 63;
    const int l15 = l & 15, lq = l >> 4;
    const int base = blockIdx.x * 128 + w * 32;

    f32x4 acc[2][8];
#pragma unroll
    for (int g = 0; g < 2; ++g)
#pragma unroll
        for (int t = 0; t < 8; ++t) acc[g][t] = (f32x4){0.f, 0.f, 0.f, 0.f};

    dual_acc<RELX2>(X1, W1h, W1l, X2, W2h, W2l, N, base, l, lq, l15, acc);

#pragma unroll
    for (int g = 0; g < 2; ++g)
#pragma unroll
        for (int t = 0; t < 8; ++t) {
            const int col = t * 16 + l15;
            const float bias = B1[col] + B2[col];
#pragma unroll
            for (int r = 0; r < 4; ++r) {
                const int grow = base + g * 16 + lq * 4 + r;
                if (grow >= N) continue;
                out[(size_t)grow * DD + col] = fmaxf(acc[g][t][r] + bias, 0.f);
            }
        }
}

// final dual GEMM with HEAD fused into the epilogue
template <bool RELX2>
__global__ __launch_bounds__(256) void gemm_dual_head_k(
        const float* __restrict__ X1,
        const unsigned short* __restrict__ W1h, const unsigned short* __restrict__ W1l,
        const float* __restrict__ B1,
        const float* __restrict__ X2,
        const unsigned short* __restrict__ W2h, const unsigned short* __restrict__ W2l,
        const float* __restrict__ B2,
        const float* __restrict__ hW, const float* __restrict__ hb,
        float* __restrict__ out, int N) {
    const int tid = threadIdx.x;
    const int w = tid >> 6, l = tid & 63;
    const int l15 = l & 15, lq = l >> 4;
    const int base = blockIdx.x * 128 + w * 32;

    f32x4 acc[2][8];
#pragma unroll
    for (int g = 0; g < 2; ++g)
#pragma unroll
        for (int t = 0; t < 8; ++t) acc[g][t] = (f32x4){0.f, 0.f, 0.f, 0.f};

    dual_acc<RELX2>(X1, W1h, W1l, X2, W2h, W2l, N, base, l, lq, l15, acc);

    float hwv[8], bv[8];
#pragma unroll
    for (int t = 0; t < 8; ++t) {
        const int col = t * 16 + l15;
        hwv[t] = hW[col];
        bv[t]  = B1[col] + B2[col];
    }
    const float hb0 = hb[0];

#pragma unroll
    for (int g = 0; g < 2; ++g)
#pragma unroll
        for (int r = 0; r < 4; ++r) {
            float s = 0.f;
#pragma unroll
            for (int t = 0; t < 8; ++t)
                s += fmaxf(acc[g][t][r] + bv[t], 0.f) * hwv[t];
            s += __shfl_xor(s, 1);
            s += __shfl_xor(s, 2);
            s += __shfl_xor(s, 4);
            s += __shfl_xor(s, 8);
            const int grow = base + g * 16 + lq * 4 + r;
            if (l15 == 0 && grow < N) out[grow] = s + hb0;
        }
}

// ---------------- host launch ----------------

extern "C" void kernel_launch(void* const* d_in, const int* in_sizes, int n_in,
                              void* d_out, int out_size, void* d_ws, size_t ws_size,
                              hipStream_t stream) {
    const float* emb_user = (const float*)d_in[0];
    const float* emb_item = (const float*)d_in[1];
    const float* head_W   = (const float*)d_in[26];
    const float* head_b   = (const float*)d_in[27];
    const int*   ue_src   = (const int*)d_in[28];
    const int*   ue_dst   = (const int*)d_in[29];
    const int*   iu_src   = (const int*)d_in[30];
    const int*   iu_dst   = (const int*)d_in[31];

    const int NU = in_sizes[0] / DD;
    const int NI = in_sizes[1] / DD;
    const int E  = in_sizes[28];

    const float* L[2][12];
    for (int l = 0; l < 2; ++l)
        for (int j = 0; j < 12; ++j) L[l][j] = (const float*)d_in[2 + l * 12 + j];

    // ---- workspace carve-up ----
    const size_t SU = (size_t)NU * DD, SI = (size_t)NI * DD;
    const size_t WPLANE = 12 * (size_t)DD * DD;
    size_t need = 0;
    auto pad256 = [](size_t b) { return (b + 255) & ~(size_t)255; };
    need += 2 * pad256(SU * 4) + pad256(SI * 4);
    need += pad256((size_t)NI * 4) + pad256((size_t)NU * 4);
    need += pad256((size_t)NI * PAD_I * 4) + pad256((size_t)NU * PAD_U * 4);
    need += 2 * pad256(WPLANE * 2);
    if (ws_size < need) return;  // fail via absmax instead of faulting

    char* w = (char*)d_ws;
    auto alloc = [&](size_t bytes) { void* p = w; w += pad256(bytes); return p; };
    float* Ua    = (float*)alloc(SU * 4);   // agg_u(L1) -> xu1
    float* Ub    = (float*)alloc(SU * 4);   // agg_u(L2)
    float* Ia    = (float*)alloc(SI * 4);   // agg_i(L1) -> xi1
    int*   deg_i = (int*)alloc((size_t)NI * 4);
    int*   deg_u = (int*)alloc((size_t)NU * 4);
    int*   adj_i = (int*)alloc((size_t)NI * PAD_I * 4);
    int*   adj_u = (int*)alloc((size_t)NU * PAD_U * 4);
    unsigned short* Whi = (unsigned short*)alloc(WPLANE * 2);
    unsigned short* Wlo = (unsigned short*)alloc(WPLANE * 2);

    auto cdiv = [](long long a, long long b) { return (int)((a + b - 1) / b); };

    // plane order per layer l (base l*6): pW1, pW2, uiWn, uiWs, iuWn, iuWs
    W12 ws;
    for (int l = 0; l < 2; ++l) {
        ws.p[l * 6 + 0] = L[l][0];
        ws.p[l * 6 + 1] = L[l][2];
        ws.p[l * 6 + 2] = L[l][4];
        ws.p[l * 6 + 3] = L[l][6];
        ws.p[l * 6 + 4] = L[l][8];
        ws.p[l * 6 + 5] = L[l][10];
    }

    // merged setup: weight split/pack + zero both degree arrays (one dispatch)
    {
        long long mx = (long long)WPLANE;
        if (NU > mx) mx = NU;
        if (NI > mx) mx = NI;
        setup_k<<<cdiv(mx, 256), 256, 0, stream>>>(ws, Whi, Wlo, deg_i, NI, deg_u, NU);
    }
    // merged adjacency build (one dispatch, both edge lists)
    fill2_k<<<cdiv(2LL * E, 256), 256, 0, stream>>>(ue_src, ue_dst, deg_i, adj_i,
                                                    iu_src, iu_dst, deg_u, adj_u, E);

    const int gI64 = cdiv(NI, 64);
    const int gU128 = cdiv(NU, 128);
    const int nbI = cdiv(NI, 4), nbU = cdiv(NU, 4);
    const size_t WM = (size_t)DD * DD;
    auto WH = [&](int l, int m) { return Whi + ((size_t)l * 6 + m) * WM; };
    auto WL = [&](int l, int m) { return Wlo + ((size_t)l * 6 + m) * WM; };

    // ---------------- layer 1 (relu applied at load from raw embeddings) ----------------
    gather2_k<true, true><<<nbI + nbU, 256, 0, stream>>>(
        emb_user, deg_i, adj_i, PAD_I, Ia, NI, nbI,
        emb_item, deg_u, adj_u, PAD_U, Ua, NU, nbU);
    gemm_dual_k<true><<<gU128, 256, 0, stream>>>(Ua, WH(0,4), WL(0,4), L[0][9],
                                                 emb_user, WH(0,5), WL(0,5), L[0][11], Ua, NU);
    item1_k<true><<<gI64, 256, 0, stream>>>(
        emb_item,
        WH(0,0), WL(0,0), L[0][1],
        WH(0,1), WL(0,1), L[0][3],
        WH(0,2), WL(0,2), L[0][5],
        WH(0,3), WL(0,3), L[0][7],
        Ia, NI, deg_i);

    // ---------------- layer 2 (item branch dead; head consumes only xu2) ----------------
    gather_mean_k<false><<<nbU, 256, 0, stream>>>(Ia, deg_u, adj_u, PAD_U, Ub, NU);
    gemm_dual_head_k<false><<<gU128, 256, 0, stream>>>(
        Ub, WH(1,4), WL(1,4), L[1][9],
        Ua, WH(1,5), WL(1,5), L[1][11],
        head_W, head_b, (float*)d_out, NU);
}

// Round 21
// 398.140 us; speedup vs baseline: 1.0734x; 1.0734x over previous
//
#include <hip/hip_runtime.h>
#include <hip/hip_bf16.h>

#define DD 128      // feature dim
#define PAD_I 64    // max item in-degree (Poisson(16); P(overflow) ~ 1e-6, guarded)
#define PAD_U 48    // max user in-degree (Poisson(8);  P(overflow) ~ 1e-9, guarded)

typedef __attribute__((ext_vector_type(8))) short bf16x8;
typedef __attribute__((ext_vector_type(4))) float f32x4;

// manual RNE fp32 -> bf16 (one-time weight prep only)
__device__ __forceinline__ unsigned short rne_bf16(float x) {
    unsigned int u = __float_as_uint(x);
    return (unsigned short)((u + 0x7FFFu + ((u >> 16) & 1u)) >> 16);
}

// load 8 contiguous fp32 (optionally relu) -> hi+lo bf16 frags (v_cvt_pk_bf16_f32 path)
template <bool R>
__device__ __forceinline__ void load_split8(const float* __restrict__ p,
                                            bf16x8& hf, bf16x8& lf) {
    float4 v0 = *reinterpret_cast<const float4*>(p);
    float4 v1 = *reinterpret_cast<const float4*>(p + 4);
    float x[8] = {v0.x, v0.y, v0.z, v0.w, v1.x, v1.y, v1.z, v1.w};
#pragma unroll
    for (int j = 0; j < 8; j += 2) {
        float a = R ? fmaxf(x[j], 0.f) : x[j];
        float b = R ? fmaxf(x[j + 1], 0.f) : x[j + 1];
        __hip_bfloat162 h2 = __float22bfloat162_rn(make_float2(a, b));
        float2 hr = __bfloat1622float2(h2);
        __hip_bfloat162 l2 = __float22bfloat162_rn(make_float2(a - hr.x, b - hr.y));
        hf[j]     = (short)__bfloat16_as_ushort(h2.x);
        hf[j + 1] = (short)__bfloat16_as_ushort(h2.y);
        lf[j]     = (short)__bfloat16_as_ushort(l2.x);
        lf[j + 1] = (short)__bfloat16_as_ushort(l2.y);
    }
}

// one 128-col GEMM stage vs packed planes, accumulating 3 split products
#define STAGE_MFMA(AH, AL, WH_, WL_, ACC)                                               \
    _Pragma("unroll")                                                                   \
    for (int kc = 0; kc < 4; ++kc) {                                                    \
        const size_t fb = ((size_t)(kc * 8) * 64 + l) * 8;                              \
        bf16x8 bh[8], bl[8];                                                            \
        _Pragma("unroll") for (int t = 0; t < 8; ++t)                                   \
            bh[t] = *reinterpret_cast<const bf16x8*>((WH_) + fb + t * 512);             \
        _Pragma("unroll") for (int t = 0; t < 8; ++t)                                   \
            bl[t] = *reinterpret_cast<const bf16x8*>((WL_) + fb + t * 512);             \
        _Pragma("unroll") for (int t = 0; t < 8; ++t)                                   \
            ACC[t] = __builtin_amdgcn_mfma_f32_16x16x32_bf16(AH[kc], bh[t], ACC[t], 0, 0, 0); \
        _Pragma("unroll") for (int t = 0; t < 8; ++t)                                   \
            ACC[t] = __builtin_amdgcn_mfma_f32_16x16x32_bf16(AL[kc], bh[t], ACC[t], 0, 0, 0); \
        _Pragma("unroll") for (int t = 0; t < 8; ++t)                                   \
            ACC[t] = __builtin_amdgcn_mfma_f32_16x16x32_bf16(AH[kc], bl[t], ACC[t], 0, 0, 0); \
    }

// ---------------- misc kernels ----------------

__global__ __launch_bounds__(256) void zeroi_k(int* __restrict__ p, int n) {
    int gid = blockIdx.x * 256 + threadIdx.x;
    if (gid < n) p[gid] = 0;
}

__global__ __launch_bounds__(256) void fill_k(const int* __restrict__ src,
                                              const int* __restrict__ dst,
                                              int* __restrict__ cur,
                                              int* __restrict__ pad, int PAD, int E) {
    int e = blockIdx.x * 256 + threadIdx.x;
    if (e >= E) return;
    int d = dst[e];
    int slot = atomicAdd(&cur[d], 1);
    if (slot < PAD) pad[(size_t)d * PAD + slot] = src[e];
}

// gather body (r15-verified): 4 rows/block, 1 wave/row. 4 x 16-lane groups:
// group p = lane>>4 owns edges e == p (mod 4); lane covers cols c*8..c*8+7.
// DIRECT pl[j] index loads (NO shfl — divergent-exec shfl is undefined, r9 lesson).
template <bool RELU>
__device__ __forceinline__ void gather_body(const float* __restrict__ feat,
                                            const int* __restrict__ cur,
                                            const int* __restrict__ pad, int PAD,
                                            float* __restrict__ out, int N, int blk) {
    int row = blk * 4 + (threadIdx.x >> 6);
    if (row >= N) return;
    int lane = threadIdx.x & 63;
    int p = lane >> 4, c = lane & 15;
    int deg = cur[row]; if (deg > PAD) deg = PAD;
    const int* pl = pad + (size_t)row * PAD;

    float4 a0 = make_float4(0.f, 0.f, 0.f, 0.f);
    float4 a1 = make_float4(0.f, 0.f, 0.f, 0.f);
    float4 b0 = make_float4(0.f, 0.f, 0.f, 0.f);
    float4 b1 = make_float4(0.f, 0.f, 0.f, 0.f);
    int j = p;
    for (; j + 4 < deg; j += 8) {
        int s0 = pl[j];
        int s1 = pl[j + 4];
        const float* q0 = feat + (size_t)s0 * DD + c * 8;
        const float* q1 = feat + (size_t)s1 * DD + c * 8;
        float4 u0 = *reinterpret_cast<const float4*>(q0);
        float4 u1 = *reinterpret_cast<const float4*>(q0 + 4);
        float4 u2 = *reinterpret_cast<const float4*>(q1);
        float4 u3 = *reinterpret_cast<const float4*>(q1 + 4);
        if (RELU) {
            u0.x = fmaxf(u0.x, 0.f); u0.y = fmaxf(u0.y, 0.f); u0.z = fmaxf(u0.z, 0.f); u0.w = fmaxf(u0.w, 0.f);
            u1.x = fmaxf(u1.x, 0.f); u1.y = fmaxf(u1.y, 0.f); u1.z = fmaxf(u1.z, 0.f); u1.w = fmaxf(u1.w, 0.f);
            u2.x = fmaxf(u2.x, 0.f); u2.y = fmaxf(u2.y, 0.f); u2.z = fmaxf(u2.z, 0.f); u2.w = fmaxf(u2.w, 0.f);
            u3.x = fmaxf(u3.x, 0.f); u3.y = fmaxf(u3.y, 0.f); u3.z = fmaxf(u3.z, 0.f); u3.w = fmaxf(u3.w, 0.f);
        }
        a0.x += u0.x; a0.y += u0.y; a0.z += u0.z; a0.w += u0.w;
        a1.x += u1.x; a1.y += u1.y; a1.z += u1.z; a1.w += u1.w;
        b0.x += u2.x; b0.y += u2.y; b0.z += u2.z; b0.w += u2.w;
        b1.x += u3.x; b1.y += u3.y; b1.z += u3.z; b1.w += u3.w;
    }
    if (j < deg) {
        int s = pl[j];
        const float* q = feat + (size_t)s * DD + c * 8;
        float4 u0 = *reinterpret_cast<const float4*>(q);
        float4 u1 = *reinterpret_cast<const float4*>(q + 4);
        if (RELU) {
            u0.x = fmaxf(u0.x, 0.f); u0.y = fmaxf(u0.y, 0.f); u0.z = fmaxf(u0.z, 0.f); u0.w = fmaxf(u0.w, 0.f);
            u1.x = fmaxf(u1.x, 0.f); u1.y = fmaxf(u1.y, 0.f); u1.z = fmaxf(u1.z, 0.f); u1.w = fmaxf(u1.w, 0.f);
        }
        a0.x += u0.x; a0.y += u0.y; a0.z += u0.z; a0.w += u0.w;
        a1.x += u1.x; a1.y += u1.y; a1.z += u1.z; a1.w += u1.w;
    }
    a0.x += b0.x; a0.y += b0.y; a0.z += b0.z; a0.w += b0.w;
    a1.x += b1.x; a1.y += b1.y; a1.z += b1.z; a1.w += b1.w;

#pragma unroll
    for (int off = 16; off <= 32; off <<= 1) {
        a0.x += __shfl_xor(a0.x, off); a0.y += __shfl_xor(a0.y, off);
        a0.z += __shfl_xor(a0.z, off); a0.w += __shfl_xor(a0.w, off);
        a1.x += __shfl_xor(a1.x, off); a1.y += __shfl_xor(a1.y, off);
        a1.z += __shfl_xor(a1.z, off); a1.w += __shfl_xor(a1.w, off);
    }
    if (p == 0) {
        float iv = 1.0f / (float)(deg > 1 ? deg : 1);
        a0.x *= iv; a0.y *= iv; a0.z *= iv; a0.w *= iv;
        a1.x *= iv; a1.y *= iv; a1.z *= iv; a1.w *= iv;
        float* o = out + (size_t)row * DD + c * 8;
        *reinterpret_cast<float4*>(o) = a0;
        *reinterpret_cast<float4*>(o + 4) = a1;
    }
}

// standalone gather (L2 user gather)
template <bool RELU>
__global__ __launch_bounds__(256) void gather_mean_k(const float* __restrict__ feat,
                                                     const int* __restrict__ cur,
                                                     const int* __restrict__ pad, int PAD,
                                                     float* __restrict__ out, int N) {
    gather_body<RELU>(feat, cur, pad, PAD, out, N, blockIdx.x);
}

// merged dual gather (L1): task1 (nb1 blocks) + task2 (nb2 blocks), 1:2 block stripe
template <bool RELU1, bool RELU2>
__global__ __launch_bounds__(256) void gather2_k(
        const float* __restrict__ feat1, const int* __restrict__ cur1,
        const int* __restrict__ pad1, int PAD1, float* __restrict__ out1, int N1, int nb1,
        const float* __restrict__ feat2, const int* __restrict__ cur2,
        const int* __restrict__ pad2, int PAD2, float* __restrict__ out2, int N2, int nb2) {
    int b = blockIdx.x;
    int which, idx;
    if (nb2 == 2 * nb1) {
        int tri = b / 3, rem = b - tri * 3;
        if (rem == 0) { which = 0; idx = tri; }
        else          { which = 1; idx = 2 * tri + rem - 1; }
    } else {
        which = (b < nb1) ? 0 : 1;
        idx = which ? (b - nb1) : b;
    }
    if (which == 0) gather_body<RELU1>(feat1, cur1, pad1, PAD1, out1, N1, idx);
    else            gather_body<RELU2>(feat2, cur2, pad2, PAD2, out2, N2, idx);
}

// ---------------- weight pre-split into PACKED fragment-order bf16 planes ----------------
// Packed p = ((kc*8 + t)*64 + lane)*8 + j  <->  W[t*16 + (lane&15)][kc*32 + (lane>>4)*8 + j]

struct W12 { const float* p[12]; };

__global__ __launch_bounds__(256) void wsplit_k(W12 ws, unsigned short* __restrict__ hi,
                                                unsigned short* __restrict__ lo) {
    int idx = blockIdx.x * 256 + threadIdx.x;
    if (idx >= 12 * DD * DD) return;
    int m = idx >> 14, pk = idx & 16383;
    int j = pk & 7, lane = (pk >> 3) & 63, t = (pk >> 9) & 7, kc = (pk >> 12) & 3;
    int src = (t * 16 + (lane & 15)) * DD + kc * 32 + (lane >> 4) * 8 + j;
    float x = ws.p[m][src];
    unsigned short h = rne_bf16(x);
    float r = x - __uint_as_float((unsigned int)h << 16);
    hi[idx] = h;
    lo[idx] = rne_bf16(r);
}

// ---------------- split-bf16 MFMA GEMM kernels ----------------
// FULL 3-product split: ah*bh + al*bh + ah*bl (~2^-18 residual).
// mfma_f32_16x16x32_bf16: A/B row = lane&15, k = (lane>>4)*8 + j; C/D col = lane&15,
// row = (lane>>4)*4 + reg.

// MERGED item layer-1 (64-row blocks, 16 rows/wave):
//   xi frags loaded ONCE (kept for uiWs operand);
//   h = relu(xi@pW1+pb1) -> LDS -> frags;
//   v = agg - (h@pW2+pb2)*(deg>0)   [agg read from Ia, FINI in registers]
//   v -> LDS -> frags;  xi1 = relu(v@uiWn + uibn + xi@uiWs + uibs) -> Ia
template <bool RELX>
__global__ __launch_bounds__(256) void item1_k(
        const float* __restrict__ X,
        const unsigned short* __restrict__ P1h, const unsigned short* __restrict__ P1l,
        const float* __restrict__ pb1,
        const unsigned short* __restrict__ P2h, const unsigned short* __restrict__ P2l,
        const float* __restrict__ pb2,
        const unsigned short* __restrict__ Nh,  const unsigned short* __restrict__ Nl,
        const float* __restrict__ bn,
        const unsigned short* __restrict__ Sh,  const unsigned short* __restrict__ Sl,
        const float* __restrict__ bs,
        float* __restrict__ Ia, int N, const int* __restrict__ deg) {
    __shared__ __align__(16) float hl[64][DD + 4];   // h, then reused for v

    const int tid = threadIdx.x;
    const int w = tid >> 6, l = tid & 63;
    const int l15 = l & 15, lq = l >> 4;

    const int rowA = blockIdx.x * 64 + w * 16 + l15;
    const int rA = rowA < N ? rowA : N - 1;
    const float* xp = X + (size_t)rA * DD;

    bf16x8 axh[4], axl[4];
#pragma unroll
    for (int kc = 0; kc < 4; ++kc)
        load_split8<RELX>(xp + kc * 32 + lq * 8, axh[kc], axl[kc]);

    f32x4 acc[8];
#pragma unroll
    for (int t = 0; t < 8; ++t) acc[t] = (f32x4){0.f, 0.f, 0.f, 0.f};

    STAGE_MFMA(axh, axl, P1h, P1l, acc)

    const int lr0 = w * 16 + lq * 4;
#pragma unroll
    for (int t = 0; t < 8; ++t) {
        const int col = t * 16 + l15;
        const float b = pb1[col];
#pragma unroll
        for (int r = 0; r < 4; ++r)
            hl[lr0 + r][col] = fmaxf(acc[t][r] + b, 0.f);
    }
    __syncthreads();

    bf16x8 ahh[4], ahl[4];
#pragma unroll
    for (int kc = 0; kc < 4; ++kc)
        load_split8<false>(&hl[w * 16 + l15][kc * 32 + lq * 8], ahh[kc], ahl[kc]);
    __syncthreads();

#pragma unroll
    for (int t = 0; t < 8; ++t) acc[t] = (f32x4){0.f, 0.f, 0.f, 0.f};
    STAGE_MFMA(ahh, ahl, P2h, P2l, acc)

#pragma unroll
    for (int t = 0; t < 8; ++t) {
        const int col = t * 16 + l15;
        const float b2v = pb2[col];
#pragma unroll
        for (int r = 0; r < 4; ++r) {
            const int grow = blockIdx.x * 64 + lr0 + r;
            const int gr = grow < N ? grow : N - 1;
            float fl = deg[gr] > 0 ? 1.f : 0.f;
            float ag = Ia[(size_t)gr * DD + col];
            hl[lr0 + r][col] = ag - (acc[t][r] + b2v) * fl;
        }
    }
    __syncthreads();

    bf16x8 avh[4], avl[4];
#pragma unroll
    for (int kc = 0; kc < 4; ++kc)
        load_split8<false>(&hl[w * 16 + l15][kc * 32 + lq * 8], avh[kc], avl[kc]);

#pragma unroll
    for (int t = 0; t < 8; ++t) acc[t] = (f32x4){0.f, 0.f, 0.f, 0.f};
    STAGE_MFMA(avh, avl, Nh, Nl, acc)
    STAGE_MFMA(axh, axl, Sh, Sl, acc)

#pragma unroll
    for (int t = 0; t < 8; ++t) {
        const int col = t * 16 + l15;
        const float bias = bn[col] + bs[col];
#pragma unroll
        for (int r = 0; r < 4; ++r) {
            const int grow = blockIdx.x * 64 + lr0 + r;
            if (grow >= N) continue;
            Ia[(size_t)grow * DD + col] = fmaxf(acc[t][r] + bias, 0.f);
        }
    }
}

// shared dual-GEMM accumulator: 128-row blocks, 32 rows/wave via 2 rowgroups
template <bool RELX2>
__device__ __forceinline__ void dual_acc(
        const float* __restrict__ X1,
        const unsigned short* __restrict__ W1h, const unsigned short* __restrict__ W1l,
        const float* __restrict__ X2,
        const unsigned short* __restrict__ W2h, const unsigned short* __restrict__ W2l,
        int N, int base, int l, int lq, int l15, f32x4 (&acc)[2][8]) {
    int rA[2];
#pragma unroll
    for (int g = 0; g < 2; ++g) {
        int r = base + g * 16 + l15;
        rA[g] = r < N ? r : N - 1;
    }
    {   // ---- X1 @ W1 ----
        bf16x8 ah[2][4], al[2][4];
#pragma unroll
        for (int g = 0; g < 2; ++g)
#pragma unroll
            for (int kc = 0; kc < 4; ++kc)
                load_split8<false>(X1 + (size_t)rA[g] * DD + kc * 32 + lq * 8, ah[g][kc], al[g][kc]);
#pragma unroll
        for (int kc = 0; kc < 4; ++kc) {
            const size_t fb = ((size_t)(kc * 8) * 64 + l) * 8;
            bf16x8 bh[8], bl[8];
#pragma unroll
            for (int t = 0; t < 8; ++t) bh[t] = *reinterpret_cast<const bf16x8*>(W1h + fb + t * 512);
#pragma unroll
            for (int t = 0; t < 8; ++t) bl[t] = *reinterpret_cast<const bf16x8*>(W1l + fb + t * 512);
#pragma unroll
            for (int g = 0; g < 2; ++g) {
#pragma unroll
                for (int t = 0; t < 8; ++t)
                    acc[g][t] = __builtin_amdgcn_mfma_f32_16x16x32_bf16(ah[g][kc], bh[t], acc[g][t], 0, 0, 0);
#pragma unroll
                for (int t = 0; t < 8; ++t)
                    acc[g][t] = __builtin_amdgcn_mfma_f32_16x16x32_bf16(al[g][kc], bh[t], acc[g][t], 0, 0, 0);
#pragma unroll
                for (int t = 0; t < 8; ++t)
                    acc[g][t] = __builtin_amdgcn_mfma_f32_16x16x32_bf16(ah[g][kc], bl[t], acc[g][t], 0, 0, 0);
            }
        }
    }
    {   // ---- X2 @ W2 ----
        bf16x8 ah[2][4], al[2][4];
#pragma unroll
        for (int g = 0; g < 2; ++g)
#pragma unroll
            for (int kc = 0; kc < 4; ++kc)
                load_split8<RELX2>(X2 + (size_t)rA[g] * DD + kc * 32 + lq * 8, ah[g][kc], al[g][kc]);
#pragma unroll
        for (int kc = 0; kc < 4; ++kc) {
            const size_t fb = ((size_t)(kc * 8) * 64 + l) * 8;
            bf16x8 bh[8], bl[8];
#pragma unroll
            for (int t = 0; t < 8; ++t) bh[t] = *reinterpret_cast<const bf16x8*>(W2h + fb + t * 512);
#pragma unroll
            for (int t = 0; t < 8; ++t) bl[t] = *reinterpret_cast<const bf16x8*>(W2l + fb + t * 512);
#pragma unroll
            for (int g = 0; g < 2; ++g) {
#pragma unroll
                for (int t = 0; t < 8; ++t)
                    acc[g][t] = __builtin_amdgcn_mfma_f32_16x16x32_bf16(ah[g][kc], bh[t], acc[g][t], 0, 0, 0);
#pragma unroll
                for (int t = 0; t < 8; ++t)
                    acc[g][t] = __builtin_amdgcn_mfma_f32_16x16x32_bf16(al[g][kc], bh[t], acc[g][t], 0, 0, 0);
#pragma unroll
                for (int t = 0; t < 8; ++t)
                    acc[g][t] = __builtin_amdgcn_mfma_f32_16x16x32_bf16(ah[g][kc], bl[t], acc[g][t], 0, 0, 0);
            }
        }
    }
}

// dual GEMM: out = relu( X1@W1^T + b1 + X2@W2^T + b2 );  out may alias X1
template <bool RELX2>
__global__ __launch_bounds__(256) void gemm_dual_k(
        const float* __restrict__ X1,
        const unsigned short* __restrict__ W1h, const unsigned short* __restrict__ W1l,
        const float* __restrict__ B1,
        const float* __restrict__ X2,
        const unsigned short* __restrict__ W2h, const unsigned short* __restrict__ W2l,
        const float* __restrict__ B2,
        float* __restrict__ out, int N) {
    const int tid = threadIdx.x;
    const int w = tid >> 6, l = tid & 63;
    const int l15 = l & 15, lq = l >> 4;
    const int base = blockIdx.x * 128 + w * 32;

    f32x4 acc[2][8];
#pragma unroll
    for (int g = 0; g < 2; ++g)
#pragma unroll
        for (int t = 0; t < 8; ++t) acc[g][t] = (f32x4){0.f, 0.f, 0.f, 0.f};

    dual_acc<RELX2>(X1, W1h, W1l, X2, W2h, W2l, N, base, l, lq, l15, acc);

#pragma unroll
    for (int g = 0; g < 2; ++g)
#pragma unroll
        for (int t = 0; t < 8; ++t) {
            const int col = t * 16 + l15;
            const float bias = B1[col] + B2[col];
#pragma unroll
            for (int r = 0; r < 4; ++r) {
                const int grow = base + g * 16 + lq * 4 + r;
                if (grow >= N) continue;
                out[(size_t)grow * DD + col] = fmaxf(acc[g][t][r] + bias, 0.f);
            }
        }
}

// final dual GEMM with HEAD fused into the epilogue
template <bool RELX2>
__global__ __launch_bounds__(256) void gemm_dual_head_k(
        const float* __restrict__ X1,
        const unsigned short* __restrict__ W1h, const unsigned short* __restrict__ W1l,
        const float* __restrict__ B1,
        const float* __restrict__ X2,
        const unsigned short* __restrict__ W2h, const unsigned short* __restrict__ W2l,
        const float* __restrict__ B2,
        const float* __restrict__ hW, const float* __restrict__ hb,
        float* __restrict__ out, int N) {
    const int tid = threadIdx.x;
    const int w = tid >> 6, l = tid & 63;
    const int l15 = l & 15, lq = l >> 4;
    const int base = blockIdx.x * 128 + w * 32;

    f32x4 acc[2][8];
#pragma unroll
    for (int g = 0; g < 2; ++g)
#pragma unroll
        for (int t = 0; t < 8; ++t) acc[g][t] = (f32x4){0.f, 0.f, 0.f, 0.f};

    dual_acc<RELX2>(X1, W1h, W1l, X2, W2h, W2l, N, base, l, lq, l15, acc);

    float hwv[8], bv[8];
#pragma unroll
    for (int t = 0; t < 8; ++t) {
        const int col = t * 16 + l15;
        hwv[t] = hW[col];
        bv[t]  = B1[col] + B2[col];
    }
    const float hb0 = hb[0];

#pragma unroll
    for (int g = 0; g < 2; ++g)
#pragma unroll
        for (int r = 0; r < 4; ++r) {
            float s = 0.f;
#pragma unroll
            for (int t = 0; t < 8; ++t)
                s += fmaxf(acc[g][t][r] + bv[t], 0.f) * hwv[t];
            s += __shfl_xor(s, 1);
            s += __shfl_xor(s, 2);
            s += __shfl_xor(s, 4);
            s += __shfl_xor(s, 8);
            const int grow = base + g * 16 + lq * 4 + r;
            if (l15 == 0 && grow < N) out[grow] = s + hb0;
        }
}

// ---------------- host launch ----------------

extern "C" void kernel_launch(void* const* d_in, const int* in_sizes, int n_in,
                              void* d_out, int out_size, void* d_ws, size_t ws_size,
                              hipStream_t stream) {
    const float* emb_user = (const float*)d_in[0];
    const float* emb_item = (const float*)d_in[1];
    const float* head_W   = (const float*)d_in[26];
    const float* head_b   = (const float*)d_in[27];
    const int*   ue_src   = (const int*)d_in[28];
    const int*   ue_dst   = (const int*)d_in[29];
    const int*   iu_src   = (const int*)d_in[30];
    const int*   iu_dst   = (const int*)d_in[31];

    const int NU = in_sizes[0] / DD;
    const int NI = in_sizes[1] / DD;
    const int E  = in_sizes[28];

    const float* L[2][12];
    for (int l = 0; l < 2; ++l)
        for (int j = 0; j < 12; ++j) L[l][j] = (const float*)d_in[2 + l * 12 + j];

    // ---- workspace carve-up ----
    const size_t SU = (size_t)NU * DD, SI = (size_t)NI * DD;
    const size_t WPLANE = 12 * (size_t)DD * DD;
    size_t need = 0;
    auto pad256 = [](size_t b) { return (b + 255) & ~(size_t)255; };
    need += 2 * pad256(SU * 4) + pad256(SI * 4);
    need += pad256((size_t)NI * 4) + pad256((size_t)NU * 4);
    need += pad256((size_t)NI * PAD_I * 4) + pad256((size_t)NU * PAD_U * 4);
    need += 2 * pad256(WPLANE * 2);
    if (ws_size < need) return;  // fail via absmax instead of faulting

    char* w = (char*)d_ws;
    auto alloc = [&](size_t bytes) { void* p = w; w += pad256(bytes); return p; };
    float* Ua    = (float*)alloc(SU * 4);   // agg_u(L1) -> xu1
    float* Ub    = (float*)alloc(SU * 4);   // agg_u(L2)
    float* Ia    = (float*)alloc(SI * 4);   // agg_i(L1) -> xi1
    int*   deg_i = (int*)alloc((size_t)NI * 4);
    int*   deg_u = (int*)alloc((size_t)NU * 4);
    int*   adj_i = (int*)alloc((size_t)NI * PAD_I * 4);
    int*   adj_u = (int*)alloc((size_t)NU * PAD_U * 4);
    unsigned short* Whi = (unsigned short*)alloc(WPLANE * 2);
    unsigned short* Wlo = (unsigned short*)alloc(WPLANE * 2);

    auto cdiv = [](long long a, long long b) { return (int)((a + b - 1) / b); };

    // pre-split + pack weights; plane order per layer l (base l*6): pW1, pW2, uiWn, uiWs, iuWn, iuWs
    W12 ws;
    for (int l = 0; l < 2; ++l) {
        ws.p[l * 6 + 0] = L[l][0];
        ws.p[l * 6 + 1] = L[l][2];
        ws.p[l * 6 + 2] = L[l][4];
        ws.p[l * 6 + 3] = L[l][6];
        ws.p[l * 6 + 4] = L[l][8];
        ws.p[l * 6 + 5] = L[l][10];
    }
    wsplit_k<<<cdiv(WPLANE, 256), 256, 0, stream>>>(ws, Whi, Wlo);

    // padded adjacency (layer-invariant)
    zeroi_k<<<cdiv(NI, 256), 256, 0, stream>>>(deg_i, NI);
    zeroi_k<<<cdiv(NU, 256), 256, 0, stream>>>(deg_u, NU);
    fill_k<<<cdiv(E, 256), 256, 0, stream>>>(ue_src, ue_dst, deg_i, adj_i, PAD_I, E);
    fill_k<<<cdiv(E, 256), 256, 0, stream>>>(iu_src, iu_dst, deg_u, adj_u, PAD_U, E);

    const int gI64 = cdiv(NI, 64);
    const int gU128 = cdiv(NU, 128);
    const int nbI = cdiv(NI, 4), nbU = cdiv(NU, 4);
    const size_t WM = (size_t)DD * DD;
    auto WH = [&](int l, int m) { return Whi + ((size_t)l * 6 + m) * WM; };
    auto WL = [&](int l, int m) { return Wlo + ((size_t)l * 6 + m) * WM; };

    // ---------------- layer 1 (relu applied at load from raw embeddings) ----------------
    gather2_k<true, true><<<nbI + nbU, 256, 0, stream>>>(
        emb_user, deg_i, adj_i, PAD_I, Ia, NI, nbI,
        emb_item, deg_u, adj_u, PAD_U, Ua, NU, nbU);
    gemm_dual_k<true><<<gU128, 256, 0, stream>>>(Ua, WH(0,4), WL(0,4), L[0][9],
                                                 emb_user, WH(0,5), WL(0,5), L[0][11], Ua, NU);
    item1_k<true><<<gI64, 256, 0, stream>>>(
        emb_item,
        WH(0,0), WL(0,0), L[0][1],
        WH(0,1), WL(0,1), L[0][3],
        WH(0,2), WL(0,2), L[0][5],
        WH(0,3), WL(0,3), L[0][7],
        Ia, NI, deg_i);

    // ---------------- layer 2 (item branch dead; head consumes only xu2) ----------------
    gather_mean_k<false><<<nbU, 256, 0, stream>>>(Ia, deg_u, adj_u, PAD_U, Ub, NU);
    gemm_dual_head_k<false><<<gU128, 256, 0, stream>>>(
        Ub, WH(1,4), WL(1,4), L[1][9],
        Ua, WH(1,5), WL(1,5), L[1][11],
        head_W, head_b, (float*)d_out, NU);
}